// Round 12
// baseline (396.935 us; speedup 1.0000x reference)
//
#include <hip/hip_runtime.h>
#include <hip/hip_bf16.h>

typedef __hip_bfloat16 bf16;
typedef unsigned short u16;
typedef u16 u16x8 __attribute__((ext_vector_type(8)));
typedef u16 u16x4v __attribute__((ext_vector_type(4)));
typedef short bf16x8 __attribute__((ext_vector_type(8)));
typedef float f32x4 __attribute__((ext_vector_type(4)));

__device__ __forceinline__ float b2f(u16 u) {
    unsigned v = ((unsigned)u) << 16;
    float f; __builtin_memcpy(&f, &v, 4); return f;
}
__device__ __forceinline__ u16 f2u(float f) {
    bf16 h = __float2bfloat16(f);
    u16 u; __builtin_memcpy(&u, &h, 2); return u;
}
__device__ __forceinline__ float sigmoidf_(float x) { return 1.f / (1.f + expf(-x)); }
__device__ __forceinline__ void load8f(const float* __restrict__ p, float* x) {
    float4 a = *reinterpret_cast<const float4*>(p);
    float4 b = *reinterpret_cast<const float4*>(p + 4);
    x[0]=a.x; x[1]=a.y; x[2]=a.z; x[3]=a.w; x[4]=b.x; x[5]=b.y; x[6]=b.z; x[7]=b.w;
}
// nt load of 8 floats (streaming inputs -> don't pollute L2/L3)
__device__ __forceinline__ void load8f_nt(const float* __restrict__ p, float* x) {
    f32x4 a = __builtin_nontemporal_load(reinterpret_cast<const f32x4*>(p));
    f32x4 b = __builtin_nontemporal_load(reinterpret_cast<const f32x4*>(p + 4));
    x[0]=a[0]; x[1]=a[1]; x[2]=a[2]; x[3]=a[3]; x[4]=b[0]; x[5]=b[1]; x[6]=b[2]; x[7]=b[3];
}
// nt store of 4 floats via native clang vector
__device__ __forceinline__ void nt_store4(float* p, float a, float b, float c, float d) {
    f32x4 v = {a, b, c, d};
    __builtin_nontemporal_store(v, reinterpret_cast<f32x4*>(p));
}
__device__ __forceinline__ void nt_store1(float* p, float a) {
    __builtin_nontemporal_store(a, p);
}

// async global->LDS, 16B per lane. LDS dest = wave-uniform base + lane*16.
__device__ __forceinline__ void gld16(const void* g, void* l) {
    typedef __attribute__((address_space(1))) const unsigned int GU;
    typedef __attribute__((address_space(3))) unsigned int LU;
    __builtin_amdgcn_global_load_lds((GU*)(unsigned long long)g,
                                     (LU*)(unsigned int)(unsigned long long)l, 16, 0, 0);
}

// ---------------------------------------------------------------------------
// m97-structure MFMA GEMM core: C = A[m][k] . Bt[n][k]^T, batched over z.
// 128x128 tile, BK=32, 256 thr (4 waves 2x2), global_load_lds, linear LDS.
// SWZ0 (batched): z=lin&7 (batch->XCD pin), t=lin>>3, x=t%GX, y=t/GX.
// SWZ1 (unbatched): chunked bijective over nwg (nwg%8==0).
// EPI 0: bf16 outb = acc*scale + bias
// EPI 1: KV dual: col<512 -> outb (k_b); col>=512 -> outb2 (v_b)
// EPI 2: Wo: out1=pd (nt); out2=pa (nt); outb=bf16(pa)
// ---------------------------------------------------------------------------
template<int EPI, int SWZ>
__device__ __forceinline__ void mfma_core(
    int lin, int nwg, short* As, short* Bs,
    const bf16* A, long long sA, int lda,
    const bf16* Bt, long long sB, int ldb,
    const float* bias, const float* bias2,
    bf16* outb, bf16* outb2, long long sO,
    float* out1, float* out2, const float* anchor,
    int N, int K, float scale, int GX)
{
    const int tid = threadIdx.x;
    int x, y, z;
    if constexpr (SWZ == 0) {
        z = lin & 7; const int t = lin >> 3; x = t % GX; y = t / GX;
    } else {
        const int q = nwg >> 3;
        const int wq = (lin & 7) * q + (lin >> 3);
        x = wq % GX; y = wq / GX; z = 0;
    }
    const int n0 = x * 128, m0 = y * 128;
    const bf16* Az = A + (long long)z * sA;
    const bf16* Bz = Bt + (long long)z * sB;
    const int lrow = tid >> 2;
    const int lcol = (tid & 3) * 8;
    const int lane = tid & 63, w = tid >> 6;
    const int wm = (w >> 1) * 64, wn = (w & 1) * 64;
    const int fr = lane & 15, fq = lane >> 4;
    char* AsW = (char*)As + w * 1024;
    char* BsW = (char*)Bs + w * 1024;

    f32x4 acc[4][4];
#pragma unroll
    for (int i = 0; i < 4; ++i)
#pragma unroll
        for (int j = 0; j < 4; ++j) acc[i][j] = f32x4{0.f, 0.f, 0.f, 0.f};

    for (int k0 = 0; k0 < K; k0 += 32) {
        const bf16* ga = Az + (long long)(m0 + lrow) * lda + (k0 + lcol);
        const bf16* gb = Bz + (long long)(n0 + lrow) * ldb + (k0 + lcol);
        gld16(ga, AsW);
        gld16(ga + 64LL * lda, AsW + 4096);
        gld16(gb, BsW);
        gld16(gb + 64LL * ldb, BsW + 4096);
        __syncthreads();

        bf16x8 af[4], bfr[4];
#pragma unroll
        for (int i = 0; i < 4; ++i)
            af[i] = *reinterpret_cast<const bf16x8*>(&As[(wm + i * 16 + fr) * 32 + fq * 8]);
#pragma unroll
        for (int j = 0; j < 4; ++j)
            bfr[j] = *reinterpret_cast<const bf16x8*>(&Bs[(wn + j * 16 + fr) * 32 + fq * 8]);
#pragma unroll
        for (int i = 0; i < 4; ++i)
#pragma unroll
            for (int j = 0; j < 4; ++j)
                acc[i][j] = __builtin_amdgcn_mfma_f32_16x16x32_bf16(af[i], bfr[j], acc[i][j], 0, 0, 0);
        __syncthreads();
    }

#pragma unroll
    for (int j = 0; j < 4; ++j) {
        const int col = n0 + wn + j * 16 + fr;
        float bv;
        if constexpr (EPI == 1) bv = (col < 512) ? bias[col] : bias2[col - 512];
        else                    bv = bias ? bias[col] : 0.f;
#pragma unroll
        for (int i = 0; i < 4; ++i) {
#pragma unroll
            for (int r = 0; r < 4; ++r) {
                const long long row = m0 + wm + i * 16 + fq * 4 + r;
                const float v = acc[i][j][r];
                if constexpr (EPI == 0) {
                    outb[(long long)z * sO + row * N + col] = __float2bfloat16(v * scale + bv);
                } else if constexpr (EPI == 1) {
                    if (col < 512) outb[row * 512 + col] = __float2bfloat16(v + bv);
                    else           outb2[row * 512 + (col - 512)] = __float2bfloat16(v + bv);
                } else {
                    const float pd = v + bv;
                    const float pa = pd + anchor[(row >> 11) * 512 + col];
                    nt_store1(&out1[row * N + col], pd);
                    nt_store1(&out2[row * N + col], pa);
                    outb[row * N + col] = __float2bfloat16(pa);
                }
            }
        }
    }
}

// ---------------------------------------------------------------------------
// standalone PV GEMM (batch-pinned)
// ---------------------------------------------------------------------------
__global__ __launch_bounds__(256)
void k_pv(const bf16* __restrict__ Pb, const bf16* __restrict__ Vt,
          bf16* __restrict__ ctx)
{
    __shared__ short SH[8192];
    mfma_core<0, 0>(blockIdx.x, 512, SH, SH + 4096,
                    Pb, 4194304LL, 2048, Vt, 1048576LL, 2048,
                    nullptr, nullptr, ctx, nullptr, 1048576LL,
                    nullptr, nullptr, nullptr, 512, 2048, 1.f, 4);
}

// ---------------------------------------------------------------------------
// merged q-projection + KV-projection (independent GEMMs, one launch).
// ---------------------------------------------------------------------------
__global__ __launch_bounds__(256)
void k_proj(const bf16* __restrict__ S0q, const bf16* __restrict__ wtq,
            const float* __restrict__ bq, bf16* __restrict__ S2,
            const bf16* __restrict__ S1, const bf16* __restrict__ wtk,
            const float* __restrict__ bk, const float* __restrict__ bv,
            bf16* __restrict__ S3, bf16* __restrict__ v_b)
{
    __shared__ short SH[8192];
    const int b = blockIdx.x;
    if (b < 512) {
        mfma_core<0, 1>(b, 512, SH, SH + 4096,
                        S0q, 0, 512, wtq, 0, 512, bq, nullptr,
                        S2, nullptr, 0, nullptr, nullptr, nullptr,
                        512, 512, 1.f, 4);
    } else {
        mfma_core<1, 1>(b - 512, 1024, SH, SH + 4096,
                        S1, 0, 512, wtk, 0, 512, bk, bv,
                        S3, v_b, 0, nullptr, nullptr, nullptr,
                        1024, 512, 1.f, 8);
    }
}

// ---------------------------------------------------------------------------
// merged V-transpose + QK^T (independent, one launch).
// ---------------------------------------------------------------------------
__global__ __launch_bounds__(256)
void k_qkt_trb(const bf16* __restrict__ v_b, bf16* __restrict__ vt,
               const bf16* __restrict__ S2q, const bf16* __restrict__ S3k,
               bf16* __restrict__ p_b, float scale)
{
    __shared__ short SH[8192];
    const int b = blockIdx.x;
    if (b < 8192) {
        u16 (*t)[36] = (u16(*)[36])SH;
        const int z = b >> 10;
        const int bi = b & 1023;
        const int h0 = (bi & 15) * 32, s0 = (bi >> 4) * 32;
        const int tr = threadIdx.x >> 3, tc = (threadIdx.x & 7) * 4;
        u16x4v a = *reinterpret_cast<const u16x4v*>(
            v_b + ((long long)z * 2048 + s0 + tr) * 512 + h0 + tc);
        t[tr][tc] = a[0]; t[tr][tc + 1] = a[1]; t[tr][tc + 2] = a[2]; t[tr][tc + 3] = a[3];
        __syncthreads();
        u16x4v o;
        o[0] = t[tc + 0][tr]; o[1] = t[tc + 1][tr]; o[2] = t[tc + 2][tr]; o[3] = t[tc + 3][tr];
        *reinterpret_cast<u16x4v*>(
            vt + (long long)z * 1048576 + (long long)(h0 + tr) * 2048 + s0 + tc) = o;
    } else {
        mfma_core<0, 0>(b - 8192, 2048, SH, SH + 4096,
                        S2q, 2048LL * 512, 512, S3k, 2048LL * 512, 512,
                        nullptr, nullptr, p_b, nullptr, 4194304LL,
                        nullptr, nullptr, nullptr, 2048, 512, scale, 16);
    }
}

// ---------------------------------------------------------------------------
// merged local/style f32->bf16 convert (nt loads) + Wo projection.
// ---------------------------------------------------------------------------
__global__ __launch_bounds__(256)
void k_wo_cvt(const float* __restrict__ local_, bf16* __restrict__ S3d,
              const float* __restrict__ style, bf16* __restrict__ S4d,
              const bf16* __restrict__ S1ctx, const bf16* __restrict__ wto,
              const float* __restrict__ bo, bf16* __restrict__ S2pa,
              float* __restrict__ o_pd, float* __restrict__ o_pa,
              const float* __restrict__ anchor)
{
    __shared__ short SH[8192];
    const int b = blockIdx.x;
    if (b < 8192) {
        const float* s = (b < 4096) ? local_ : style;
        bf16* d = (b < 4096) ? S3d : S4d;
        const long long i = ((long long)(b & 4095) * 256 + threadIdx.x) * 8;
        float x[8]; load8f_nt(s + i, x);
        u16x8 o;
#pragma unroll
        for (int j = 0; j < 8; ++j) o[j] = f2u(x[j]);
        *reinterpret_cast<u16x8*>(d + i) = o;
    } else {
        mfma_core<2, 1>(b - 8192, 512, SH, SH + 4096,
                        S1ctx, 0, 512, wto, 0, 512, bo, nullptr,
                        S2pa, nullptr, 0, o_pd, o_pa, anchor,
                        512, 512, 1.f, 4);
    }
}

// ---------------------------------------------------------------------------
// Softmax over bf16 logit rows of 2048 (one block/row): writes f32 attn (nt)
// and normalized bf16 P in-place.
// ---------------------------------------------------------------------------
__global__ __launch_bounds__(256)
void k_softmax_b(bf16* __restrict__ Lb, float* __restrict__ attn)
{
    __shared__ float redm[4], reds[4];
    const long long row = blockIdx.x;
    bf16* lp = Lb + row * 2048;
    float* ap = attn + row * 2048;
    const int tid = threadIdx.x;

    u16x8 u = *reinterpret_cast<const u16x8*>(lp + tid * 8);
    float x[8];
    float mx = -1e30f;
#pragma unroll
    for (int j = 0; j < 8; ++j) { x[j] = b2f(u[j]); mx = fmaxf(mx, x[j]); }
#pragma unroll
    for (int off = 32; off; off >>= 1) mx = fmaxf(mx, __shfl_xor(mx, off));
    if ((tid & 63) == 0) redm[tid >> 6] = mx;
    __syncthreads();
    mx = fmaxf(fmaxf(redm[0], redm[1]), fmaxf(redm[2], redm[3]));

    float s = 0.f;
#pragma unroll
    for (int j = 0; j < 8; ++j) { x[j] = __expf(x[j] - mx); s += x[j]; }
#pragma unroll
    for (int off = 32; off; off >>= 1) s += __shfl_xor(s, off);
    if ((tid & 63) == 0) reds[tid >> 6] = s;
    __syncthreads();
    const float inv = 1.f / (reds[0] + reds[1] + reds[2] + reds[3]);

    u16x8 ob;
#pragma unroll
    for (int j = 0; j < 8; ++j) { x[j] *= inv; ob[j] = f2u(x[j]); }
    nt_store4(ap + tid * 8,     x[0], x[1], x[2], x[3]);
    nt_store4(ap + tid * 8 + 4, x[4], x[5], x[6], x[7]);
    *reinterpret_cast<u16x8*>(lp + tid * 8) = ob;
}

// ---------------------------------------------------------------------------
// Concat-gather MFMA GEMM + fused hidden GEMV partial (gate MLPs).
// R9-proven decode: grid 512, xt=wq&3, m0=(wq>>2)*128, full K 0..2048.
// ---------------------------------------------------------------------------
__global__ __launch_bounds__(256)
void k_cat(const bf16* __restrict__ s0b, const bf16* __restrict__ s1b,
           const bf16* __restrict__ s2b, const bf16* __restrict__ s3b,
           int mode2,
           const bf16* __restrict__ Bt, const float* __restrict__ bias,
           const float* __restrict__ w2, float* __restrict__ part)
{
    __shared__ short As[4096];
    __shared__ short Bs[4096];
    __shared__ float pl[128][2];
    const int tid = threadIdx.x;
    const int lin = blockIdx.x;
    const int q = (int)gridDim.x >> 3;
    const int wq = (lin & 7) * q + (lin >> 3);
    const int xt = wq & 3;
    const int n0 = xt * 128, m0 = (wq >> 2) * 128;
    const int lrow = tid >> 2;
    const int lcol = (tid & 3) * 8;
    const int lane = tid & 63, w = tid >> 6;
    const int wm = (w >> 1) * 64, wn = (w & 1) * 64;
    const int fr = lane & 15, fq = lane >> 4;
    char* AsW = (char*)As + w * 1024;
    char* BsW = (char*)Bs + w * 1024;

    f32x4 acc[4][4];
#pragma unroll
    for (int i = 0; i < 4; ++i)
#pragma unroll
        for (int j = 0; j < 4; ++j) acc[i][j] = f32x4{0.f, 0.f, 0.f, 0.f};

    for (int k0 = 0; k0 < 2048; k0 += 32) {
        const int si = k0 >> 9;
        const bf16* sp = si == 0 ? s0b : si == 1 ? s1b : si == 2 ? s2b : s3b;
        const int kloc = (k0 & 511) + lcol;
        const int r = m0 + lrow;
        long long ro0, ro1;
        if (si == 2 && mode2) { ro0 = (long long)(r >> 11) * 512; ro1 = ro0; }
        else                  { ro0 = (long long)r * 512; ro1 = ro0 + 64LL * 512; }
        gld16(sp + ro0 + kloc, AsW);
        gld16(sp + ro1 + kloc, AsW + 4096);
        const bf16* gb = Bt + (long long)(n0 + lrow) * 2048 + (k0 + lcol);
        gld16(gb, BsW);
        gld16(gb + 64LL * 2048, BsW + 4096);
        __syncthreads();

        bf16x8 af[4], bfr[4];
#pragma unroll
        for (int i = 0; i < 4; ++i)
            af[i] = *reinterpret_cast<const bf16x8*>(&As[(wm + i * 16 + fr) * 32 + fq * 8]);
#pragma unroll
        for (int j = 0; j < 4; ++j)
            bfr[j] = *reinterpret_cast<const bf16x8*>(&Bs[(wn + j * 16 + fr) * 32 + fq * 8]);
#pragma unroll
        for (int i = 0; i < 4; ++i)
#pragma unroll
            for (int j = 0; j < 4; ++j)
                acc[i][j] = __builtin_amdgcn_mfma_f32_16x16x32_bf16(af[i], bfr[j], acc[i][j], 0, 0, 0);
        __syncthreads();
    }

    // fused second-layer partial: relu(acc+b1)*w2, summed over block's 128 cols
    float pt[4][4];
#pragma unroll
    for (int i = 0; i < 4; ++i)
#pragma unroll
        for (int r = 0; r < 4; ++r) pt[i][r] = 0.f;
#pragma unroll
    for (int j = 0; j < 4; ++j) {
        const int col = n0 + wn + j * 16 + fr;
        const float bv = bias[col];
        const float wv = w2[col];
#pragma unroll
        for (int i = 0; i < 4; ++i)
#pragma unroll
            for (int r = 0; r < 4; ++r)
                pt[i][r] = fmaf(fmaxf(acc[i][j][r] + bv, 0.f), wv, pt[i][r]);
    }
#pragma unroll
    for (int off = 1; off < 16; off <<= 1)
#pragma unroll
        for (int i = 0; i < 4; ++i)
#pragma unroll
            for (int r = 0; r < 4; ++r)
                pt[i][r] += __shfl_xor(pt[i][r], off);
    if (fr == 0)
#pragma unroll
        for (int i = 0; i < 4; ++i)
#pragma unroll
            for (int r = 0; r < 4; ++r)
                pl[wm + i * 16 + fq * 4 + r][wn >> 6] = pt[i][r];
    __syncthreads();
    if (tid < 128)
        part[(long long)(m0 + tid) * 4 + xt] = pl[tid][0] + pl[tid][1];
}

// ---------------------------------------------------------------------------
// Fat prologue: query/gmem/anchor f32->bf16 (nt loads) + 6 weight transposes.
// ---------------------------------------------------------------------------
__global__ __launch_bounds__(256)
void k_prologue(const float* __restrict__ query, bf16* __restrict__ qb,
                const float* __restrict__ gmem, bf16* __restrict__ gb,
                const float* __restrict__ anchor, bf16* __restrict__ anb,
                const float* Wq, bf16* wtq, const float* Wk, bf16* wtk,
                const float* Wv, bf16* wtv, const float* Wo, bf16* wto,
                const float* Wm1, bf16* wtm1, const float* Wg1, bf16* wtg1)
{
    __shared__ float tls[32][33];
    const int b = blockIdx.x;
    const int tid = threadIdx.x;
    if (b < 8192) {
        const float* s = (b < 4096) ? query : gmem;
        bf16* d = (b < 4096) ? qb : gb;
        const long long i = ((long long)(b & 4095) * 256 + tid) * 8;
        float x[8]; load8f_nt(s + i, x);
        u16x8 o;
#pragma unroll
        for (int j = 0; j < 8; ++j) o[j] = f2u(x[j]);
        *reinterpret_cast<u16x8*>(d + i) = o;
        return;
    }
    if (b < 8194) {
        const int i = ((b - 8192) * 256 + tid) * 8;
        if (i < 4096) {
            float x[8]; load8f(anchor + i, x);
            u16x8 o;
#pragma unroll
            for (int j = 0; j < 8; ++j) o[j] = f2u(x[j]);
            *reinterpret_cast<u16x8*>(anb + i) = o;
        }
        return;
    }
    const float* s; bf16* d; int R, C, ti;
    if (b < 9218) {
        const int bi = b - 8194; const int zz = bi >> 8; ti = bi & 255;
        s = zz == 0 ? Wq : zz == 1 ? Wk : zz == 2 ? Wv : Wo;
        d = zz == 0 ? wtq : zz == 1 ? wtk : zz == 2 ? wtv : wto;
        R = 512; C = 512;
    } else {
        const int bi = b - 9218; const int zz = bi >> 10; ti = bi & 1023;
        s = zz ? Wg1 : Wm1; d = zz ? wtg1 : wtm1;
        R = 2048; C = 512;
    }
    const int c0 = (ti & 15) * 32, r0 = (ti >> 4) * 32;
    const int tr = tid >> 3, tc = (tid & 7) * 4;
    float4 v = *reinterpret_cast<const float4*>(s + (long long)(r0 + tr) * C + c0 + tc);
    tls[tr][tc] = v.x; tls[tr][tc + 1] = v.y; tls[tr][tc + 2] = v.z; tls[tr][tc + 3] = v.w;
    __syncthreads();
    u16x4v o;
    o[0] = f2u(tls[tc + 0][tr]); o[1] = f2u(tls[tc + 1][tr]);
    o[2] = f2u(tls[tc + 2][tr]); o[3] = f2u(tls[tc + 3][tr]);
    *reinterpret_cast<u16x4v*>(d + (long long)(c0 + tr) * R + r0 + tc) = o;
}

// ---------------------------------------------------------------------------
// mix finisher + slerp, one wave per row (nt on f32 cand/cdelta).
// ---------------------------------------------------------------------------
__global__ __launch_bounds__(64)
void k_gate_slerp(const float* __restrict__ part, const float* __restrict__ b2,
                  const bf16* __restrict__ priorb, const bf16* __restrict__ localb,
                  const float* __restrict__ anchor,
                  float* __restrict__ o_mix,
                  float* __restrict__ cand, float* __restrict__ cdelta,
                  bf16* __restrict__ candb)
{
    const int row = blockIdx.x;
    const int lane = threadIdx.x;
    float v = (lane < 4) ? part[(long long)row * 4 + lane] : 0.f;
    v += __shfl_xor(v, 1);
    v += __shfl_xor(v, 2);
    const float logit = __shfl(v, 0) + b2[0];
    float t = sigmoidf_(logit - 0.25f);
    if (lane == 0) o_mix[row] = t;
    t = fminf(fmaxf(t, 0.f), 1.f);

    const long long base = (long long)row * 512 + lane * 8;
    const long long abase = (long long)(row >> 11) * 512 + lane * 8;
    u16x8 ua = *reinterpret_cast<const u16x8*>(priorb + base);
    u16x8 ub = *reinterpret_cast<const u16x8*>(localb + base);
    float a[8], b[8];
    float sa = 0.f, sb = 0.f, sab = 0.f;
#pragma unroll
    for (int j = 0; j < 8; ++j) {
        a[j] = b2f(ua[j]); b[j] = b2f(ub[j]);
        sa = fmaf(a[j], a[j], sa); sb = fmaf(b[j], b[j], sb); sab = fmaf(a[j], b[j], sab);
    }
#pragma unroll
    for (int off = 1; off < 64; off <<= 1) {
        sa += __shfl_xor(sa, off); sb += __shfl_xor(sb, off); sab += __shfl_xor(sab, off);
    }
    const float eps = 1e-6f;
    float na = fmaxf(sqrtf(sa), eps), nb = fmaxf(sqrtf(sb), eps);
    float dot = sab / (na * nb);
    dot = fminf(fmaxf(dot, -1.f + eps), 1.f - eps);
    float omega = acosf(dot);
    float so = fmaxf(sinf(omega), eps);
    float sca = sinf((1.f - t) * omega) / so;
    float scb = sinf(t * omega) / so;

    float an[8];
    load8f(anchor + abase, an);
    float c0[8], d0[8];
    u16x8 cb;
#pragma unroll
    for (int j = 0; j < 8; ++j) {
        c0[j] = sca * a[j] + scb * b[j];
        d0[j] = c0[j] - an[j];
        cb[j] = f2u(c0[j]);
    }
    nt_store4(cand + base,       c0[0], c0[1], c0[2], c0[3]);
    nt_store4(cand + base + 4,   c0[4], c0[5], c0[6], c0[7]);
    nt_store4(cdelta + base,     d0[0], d0[1], d0[2], d0[3]);
    nt_store4(cdelta + base + 4, d0[4], d0[5], d0[6], d0[7]);
    *reinterpret_cast<u16x8*>(candb + base) = cb;
}

// ---------------------------------------------------------------------------
// variation finisher: thread per row.
// ---------------------------------------------------------------------------
__global__ __launch_bounds__(256)
void k_gate_var(const float* __restrict__ part, const float* __restrict__ b2,
                float* __restrict__ o_vl, float* __restrict__ o_vg)
{
    const long long row = (long long)blockIdx.x * 256 + threadIdx.x;
    float4 p = *reinterpret_cast<const float4*>(part + row * 4);
    const float logit = (p.x + p.y) + (p.z + p.w) + b2[0];
    o_vl[row] = logit;
    o_vg[row] = sigmoidf_(logit - 1.0f);
}

// ---------------------------------------------------------------------------
extern "C" void kernel_launch(void* const* d_in, const int* in_sizes, int n_in,
                              void* d_out, int out_size, void* d_ws, size_t ws_size,
                              hipStream_t stream)
{
    const float* query  = (const float*)d_in[0];
    const float* anchor = (const float*)d_in[1];
    const float* gmem   = (const float*)d_in[2];
    const float* local_ = (const float*)d_in[3];
    const float* style  = (const float*)d_in[4];
    const float* Wq = (const float*)d_in[5];   const float* bq = (const float*)d_in[6];
    const float* Wk = (const float*)d_in[7];   const float* bk = (const float*)d_in[8];
    const float* Wv = (const float*)d_in[9];   const float* bv = (const float*)d_in[10];
    const float* Wo = (const float*)d_in[11];  const float* bo = (const float*)d_in[12];
    const float* Wm1 = (const float*)d_in[13]; const float* bm1 = (const float*)d_in[14];
    const float* Wm2 = (const float*)d_in[15]; const float* bm2 = (const float*)d_in[16];
    const float* Wg1 = (const float*)d_in[17]; const float* bg1 = (const float*)d_in[18];
    const float* Wg2 = (const float*)d_in[19]; const float* bg2 = (const float*)d_in[20];

    float* out = (float*)d_out;
    const long long SHE = 8388608LL;             // B*S*H elems
    float* o_attn = out;                         // [B,S,M]
    float* o_pd   = out + 33554432LL;            // prior_delta
    float* o_pa   = o_pd + SHE;                  // prior_absolute
    float* o_mix  = o_pa + SHE;                  // mix [16384]
    float* o_ca   = o_mix + 16384;               // candidate_absolute
    float* o_cd   = o_ca + SHE;                  // candidate_delta
    float* o_vl   = o_cd + SHE;                  // variation_logit
    float* o_vg   = o_vl + 16384;                // variation_gate

    // ws slots (bf16, 8.4M elems each, aggressively reused):
    bf16* S0q = (bf16*)d_ws;       // query_b (whole run)
    bf16* S1  = S0q + SHE;         // gmem_b -> ctx_b
    bf16* S2  = S1 + SHE;          // q_b -> pa_b -> ca_b
    bf16* S3  = S2 + SHE;          // k_b -> local_b
    bf16* S4  = S3 + SHE;          // v_t -> style_b
    bf16* wtq = S4 + SHE;          // transposed weights (bf16)
    bf16* wtk = wtq + 262144;      // wtk,wtv contiguous => KV merged B [1024][512]
    bf16* wtv = wtk + 262144;
    bf16* wto = wtv + 262144;
    bf16* wtm1 = wto + 262144;     // [512][2048]
    bf16* wtg1 = wtm1 + 1048576;   // [512][2048]
    bf16* anb  = wtg1 + 1048576;   // anchor_b [8,512]
    float* part_m = (float*)(anb + 4096);  // [16384][4]
    float* part_v = part_m + 65536;        // [16384][4]
    bf16* p_b  = (bf16*)o_ca;      // bf16 logits->P in d_out o_ca+o_cd (67 MB)
    bf16* v_b  = (bf16*)o_attn;    // row-major v staging in o_attn (dead until softmax)

    const float invSqrtH = 0.04419417382415922f; // 1/sqrt(512)

    // fat prologue: all conversions + weight transposes
    k_prologue<<<11266, 256, 0, stream>>>(query, S0q, gmem, S1, anchor, anb,
        Wq, wtq, Wk, wtk, Wv, wtv, Wo, wto, Wm1, wtm1, Wg1, wtg1);
    // merged q-projection + KV-projection
    k_proj<<<1536, 256, 0, stream>>>(S0q, wtq, bq, S2, S1, wtk, bk, bv, S3, v_b);
    // merged V-transpose (v_b -> S4) + QK^T (q.k^T -> p_b)
    k_qkt_trb<<<10240, 256, 0, stream>>>(v_b, S4, S2, S3, p_b, invSqrtH);
    // softmax: bf16 logits -> f32 attn (nt) + normalized bf16 P in place
    k_softmax_b<<<16384, 256, 0, stream>>>(p_b, o_attn);
    // PV (batch-pinned): P_b . v_t^T -> ctx_b (S1)
    k_pv<<<512, 256, 0, stream>>>(p_b, S4, S1);
    // merged local/style cvt (-> S3,S4) + Wo projection (pd/pa nt, pa_b -> S2)
    k_wo_cvt<<<8704, 256, 0, stream>>>(local_, S3, style, S4, S1, wto, bo,
        S2, o_pd, o_pa, anchor);
    // mix gate MLP -> per-block partials
    k_cat<<<512, 256, 0, stream>>>(S0q, S2, S3, S4, 0, wtm1, bm1, Wm2, part_m);
    // mix finisher + slerp (reads pa_b, writes ca/cd nt + ca_b in place)
    k_gate_slerp<<<16384, 64, 0, stream>>>(part_m, bm2, S2, S3, anchor,
        o_mix, o_ca, o_cd, S2);
    // variation gate MLP (src2 = anchor_b broadcast)
    k_cat<<<512, 256, 0, stream>>>(S0q, S2, anb, S4, 1, wtg1, bg1, Wg2, part_v);
    k_gate_var<<<64, 256, 0, stream>>>(part_v, bg2, o_vl, o_vg);
}